// Round 8
// baseline (277.734 us; speedup 1.0000x reference)
//
#include <hip/hip_runtime.h>
#include <hip/hip_bf16.h>

using short8   = __attribute__((ext_vector_type(8))) short;
using floatx4  = __attribute__((ext_vector_type(4))) float;
using floatx16 = __attribute__((ext_vector_type(16))) float;

#define KDIM 768
#define QSCALE 0.18033688011112042f   // 0.125 * log2(e)
#define N1 (8192 * 768)
#define N2 (2304 * 768)
#define N3 (768 * 768)

__device__ __forceinline__ short f2bf(float f) {
    union { float f; unsigned u; } v; v.f = f;
    unsigned r = v.u + 0x7fffu + ((v.u >> 16) & 1u);
    return (short)(r >> 16);
}

__device__ __forceinline__ unsigned pack2bf(float a, float b) {
    __hip_bfloat162 h = __float22bfloat162_rn(float2{a, b});
    union { __hip_bfloat162 h; unsigned u; } c; c.h = h;
    return c.u;
}

__device__ __forceinline__ float fast_exp2(float x) {
#if __has_builtin(__builtin_amdgcn_exp2f)
    return __builtin_amdgcn_exp2f(x);
#else
    return exp2f(x);
#endif
}

__device__ __forceinline__ void async16(const void* g, void* l) {
    __builtin_amdgcn_global_load_lds((const __attribute__((address_space(1))) void*)g,
                                     (__attribute__((address_space(3))) void*)l, 16, 0, 0);
}

// ---------------- fused fp32 -> bf16 convert for all three inputs ----------------
__global__ void cvt_all(const float* __restrict__ a, const float* __restrict__ b,
                        const float* __restrict__ c, short* __restrict__ oa,
                        short* __restrict__ ob, short* __restrict__ oc) {
    int i = (blockIdx.x * blockDim.x + threadIdx.x) * 4;
    const float* src; short* dst;
    if (i < N1)            { src = a + i;            dst = oa + i; }
    else if (i < N1 + N2)  { src = b + (i - N1);     dst = ob + (i - N1); }
    else if (i < N1+N2+N3) { src = c + (i - N1 - N2); dst = oc + (i - N1 - N2); }
    else return;
    float4 v = *(const float4*)src;
    short4 o;
    o.x = f2bf(v.x); o.y = f2bf(v.y); o.z = f2bf(v.z); o.w = f2bf(v.w);
    *(short4*)dst = o;
}

// ---------------- QKV GEMM: C[8192,2304] = X @ W^T -> Q/K [bh][s][64], V DIRECT to Vt ----------------
// XCD-aware remap: XCD c = fid%8 owns M-rows [8c, 8c+8).
// Epilogue v3: C-tile staged through LDS, coalesced 16B/lane write-back.
// V blocks (nx 12..17) are stored TRANSPOSED + sigma-key-permuted into LDS and written
// straight to Vt [bh][e][2048] -- transpose_v kernel fused away (saves a kernel + 25 MB
// of Vb round-trip). sigma7 = swap bits 2,3 (involution): storing at [col][sigma(row)]
// and reading linearly at p yields row sigma(p), identical to the old transpose_v output.
__global__ __launch_bounds__(256) void gemm_qkv(
    const short* __restrict__ X, const short* __restrict__ W,
    const float* __restrict__ bias,
    short* __restrict__ Qb, short* __restrict__ Kb, short* __restrict__ Vt)
{
    __shared__ short Smem[128 * 144];          // 36 KB: As/Bs (16 KB) during K-loop, C-tile after
    short* As = Smem;                          // 128*32
    short* Bs = Smem + 128 * 32;               // 128*32
    int tid = threadIdx.x;
    int w = tid >> 6, l = tid & 63;
    int lane16 = l & 15, quad = l >> 4;
    int wm = w & 1, wn = w >> 1;

    int fid = blockIdx.x + 18 * blockIdx.y;   // 0..1151, dispatch order
    int c = fid & 7, s = fid >> 3;            // s in 0..143
    int my = c * 8 + s / 18;                  // 0..63
    int nx = s % 18;                          // 0..17
    int m0 = my * 128, n0 = nx * 128;

    floatx4 acc[4][4] = {};

    int srow = w * 32 + (l >> 2);
    int scol = (l & 3) * 8;
    const short* Xg = X + (size_t)(m0 + srow) * KDIM + scol;
    const short* Wg = W + (size_t)(n0 + srow) * KDIM + scol;
    short* AsW = As + (w * 32) * 32;
    short* BsW = Bs + (w * 32) * 32;

    for (int kb = 0; kb < KDIM; kb += 32) {
        __syncthreads();
        async16(Xg + kb,              AsW);
        async16(Xg + kb + 16 * KDIM,  AsW + 16 * 32);
        async16(Wg + kb,              BsW);
        async16(Wg + kb + 16 * KDIM,  BsW + 16 * 32);
        __syncthreads();
        short8 a[4], b[4];
#pragma unroll
        for (int mt = 0; mt < 4; mt++) a[mt] = *(const short8*)(As + (wm * 64 + mt * 16 + lane16) * 32 + quad * 8);
#pragma unroll
        for (int nt = 0; nt < 4; nt++) b[nt] = *(const short8*)(Bs + (wn * 64 + nt * 16 + lane16) * 32 + quad * 8);
#pragma unroll
        for (int mt = 0; mt < 4; mt++)
#pragma unroll
            for (int nt = 0; nt < 4; nt++)
                acc[mt][nt] = __builtin_amdgcn_mfma_f32_16x16x32_bf16(a[mt], b[nt], acc[mt][nt], 0, 0, 0);
    }

    // ---- epilogue ----
    int qkv = nx / 6;                          // whole block is one of Q/K/V
    float sc = (qkv == 0) ? (float)QSCALE : 1.0f;
    int h0 = (nx - qkv * 6) * 2;               // first of the 2 heads this block covers
    int b_ = m0 >> 11, s0 = m0 & 2047;

    __syncthreads();                           // all MFMA reads of As/Bs complete
    if (qkv < 2) {
        // Q/K: [s][col] tile, coalesced [bh][s][64] write-back
        short* dst = (qkv == 0) ? Qb : Kb;
#pragma unroll
        for (int mt = 0; mt < 4; mt++) {
            int rowl = wm * 64 + mt * 16 + quad * 4;
#pragma unroll
            for (int nt = 0; nt < 4; nt++) {
                int coll = wn * 64 + nt * 16 + lane16;
                float bv = bias[n0 + coll];
#pragma unroll
                for (int r = 0; r < 4; r++)
                    Smem[(rowl + r) * 144 + coll] = f2bf((acc[mt][nt][r] + bv) * sc);
            }
        }
        __syncthreads();
#pragma unroll
        for (int i = 0; i < 8; i++) {
            int slot = i * 256 + tid;
            int ch = slot >> 10;
            int rem2 = slot & 1023;
            int s_loc = rem2 >> 3, e8 = rem2 & 7;
            short8 v = *(const short8*)(Smem + s_loc * 144 + ch * 64 + e8 * 8);
            *(short8*)(dst + (((size_t)(b_ * 12 + h0 + ch)) * 2048 + s0 + s_loc) * 64 + e8 * 8) = v;
        }
    } else {
        // V: transposed + sigma-permuted tile [col][sigma(row)], coalesced Vt [bh][e][2048] write
#pragma unroll
        for (int mt = 0; mt < 4; mt++) {
            int rowl = wm * 64 + mt * 16 + quad * 4;
#pragma unroll
            for (int nt = 0; nt < 4; nt++) {
                int coll = wn * 64 + nt * 16 + lane16;
                float bv = bias[n0 + coll];
#pragma unroll
                for (int r = 0; r < 4; r++) {
                    int row = rowl + r;
                    int sig = (row & 0x73) | ((row & 4) << 1) | ((row & 8) >> 1);  // sigma on bits 2,3
                    Smem[coll * 144 + sig] = f2bf(acc[mt][nt][r] + bv);
                }
            }
        }
        __syncthreads();
#pragma unroll
        for (int i = 0; i < 8; i++) {
            int slot = i * 256 + tid;               // 2048 short8 slots: 2 heads x 64 e x 16 chunks
            int ch = slot >> 10;
            int rem2 = slot & 1023;
            int e_loc = rem2 >> 4, t8 = rem2 & 15;
            short8 v = *(const short8*)(Smem + (ch * 64 + e_loc) * 144 + t8 * 8);
            *(short8*)(Vt + ((size_t)((b_ * 12 + h0 + ch) * 64 + e_loc)) * 2048 + s0 + t8 * 8) = v;
        }
    }
}

// ---------------- flash attention, 32x32x16 MFMA, transposed QK^T, P in registers ----------------
// 64 q-rows PER WAVE v2 (register-disciplined): two q-groups share every K/V fragment ->
// per-CU LDS read traffic HALVES (r7 PMC: LDS pipe ~57-64% = largest consumer) at constant
// MFMA work. r6's spill fixed by per-nt just-in-time kf loads + immediate exp2 (never both
// S-tiles + kf + vf live). 128-thr blocks, grid (16,48) = 3 blocks/CU (48 KB LDS tbuf).
// Schedule = r5's proven triple-buffer + counted vmcnt (now vmcnt(8): 8 async16/tile/thread).
// XCD remap + setprio kept.
__global__ __launch_bounds__(128) void attn(
    const short* __restrict__ Qb, const short* __restrict__ Kb,
    const short* __restrict__ Vt, short* __restrict__ Ctx)
{
    __shared__ short Ks[3][512 * 8];   // K tiles: [key 64][e 64], swizzled slots, 3 buffers
    __shared__ short Vs[3][512 * 8];   // V^T tiles: [e 64][64 sigma-ordered keys], 3 buffers
    int tid = threadIdx.x, w = tid >> 6, l = tid & 63;
    int l32 = l & 31, half = l >> 5;

    int fid = blockIdx.x + (blockIdx.y << 4);   // 0..767, dispatch order
    int c = fid & 7, sfl = fid >> 3;            // sfl in 0..95
    int bh = c * 6 + (sfl >> 4);                // XCD c owns 6 heads
    int qt = sfl & 15;

    const short* Qh  = Qb + (size_t)bh * 2048 * 64;
    const short* Kh  = Kb + (size_t)bh * 2048 * 64;
    const short* Vth = Vt + (size_t)bh * 64 * 2048;
    int qbase = qt * 128 + w * 64;              // wave owns 64 q-rows

    // staging: 512 slots per array over 128 threads, 4 async16 per thread per array
    const short* kSrc[4];
    const short* vSrc[4];
    int dOff[4];
#pragma unroll
    for (int i = 0; i < 4; i++) {
        int slot = i * 128 + tid;
        int row = slot >> 3;
        int g = (slot & 7) ^ (row & 7);
        kSrc[i] = Kh + (size_t)row * 64 + g * 8;        // + kt*64*64
        vSrc[i] = Vth + (size_t)row * 2048 + g * 8;     // + kt*64
        dOff[i] = (i * 128 + w * 64) * 8;               // wave-uniform base (shorts)
    }

    // Q fragments (B operand), two q-groups (issued first -> retire first)
    short8 qf[2][4];
#pragma unroll
    for (int qg = 0; qg < 2; qg++)
#pragma unroll
        for (int ks = 0; ks < 4; ks++)
            qf[qg][ks] = *(const short8*)(Qh + (size_t)(qbase + qg * 32 + l32) * 64 + ks * 16 + half * 8);

    // prologue: stage tiles 0 and 1 into buffers 0 and 1
#pragma unroll
    for (int i = 0; i < 4; i++) {
        async16(kSrc[i],        &Ks[0][0] + dOff[i]);
        async16(vSrc[i],        &Vs[0][0] + dOff[i]);
    }
#pragma unroll
    for (int i = 0; i < 4; i++) {
        async16(kSrc[i] + 4096, &Ks[1][0] + dOff[i]);
        async16(vSrc[i] + 64,   &Vs[1][0] + dOff[i]);
    }

    float lsum0 = 0.f, lsum1 = 0.f;
    floatx16 acc[2][2] = {};                    // [e-half][q-group], fully unrolled indexing
    int sw = l32 & 7;   // row-swizzle term (row & 7 == l32 & 7 for row = nt*32 + l32)

    union upa { short8 s8; unsigned u[4]; };

    int cur = 0;        // kt % 3, maintained incrementally
    for (int kt = 0; kt < 32; kt++) {
        // counted wait: tile kt's 8 loads landed (kt+1's 8 stay in flight); last tile drains
        if (kt < 31) { asm volatile("s_waitcnt vmcnt(8)" ::: "memory"); }
        else         { asm volatile("s_waitcnt vmcnt(0)" ::: "memory"); }
        __builtin_amdgcn_s_barrier();     // all waves' tile-kt loads visible; buf reuse safe

        // issue tile kt+2's stage into buffer (kt+2)%3  (lands ~2 tiles from now)
        int pf = kt + 2;
        if (pf < 32) {
            int pb = cur >= 1 ? cur - 1 : cur + 2;    // (kt+2)%3 == (kt-1)%3
#pragma unroll
            for (int i = 0; i < 4; i++) {
                async16(kSrc[i] + (size_t)pf * 4096, &Ks[pb][0] + dOff[i]);
                async16(vSrc[i] + (size_t)pf * 64,   &Vs[pb][0] + dOff[i]);
            }
        }

        const short* Kcur = &Ks[cur][0];
        const short* Vcur = &Vs[cur][0];

        // S^T per nt: JIT kf loads, two q-group chains, immediate exp2 (keeps live-set small)
        upa pa0[4], pa1[4];
#pragma unroll
        for (int nt = 0; nt < 2; nt++) {
            int rowb = (nt * 32 + l32) * 8;
            short8 kf[4];
#pragma unroll
            for (int ks = 0; ks < 4; ks++)
                kf[ks] = *(const short8*)(Kcur + (size_t)(rowb + ((ks * 2 + half) ^ sw)) * 8);
            floatx16 c0 = {}, c1 = {};
            __builtin_amdgcn_s_setprio(1);
#pragma unroll
            for (int ks = 0; ks < 4; ks++) {
                c0 = __builtin_amdgcn_mfma_f32_32x32x16_bf16(kf[ks], qf[0][ks], c0, 0, 0, 0);
                c1 = __builtin_amdgcn_mfma_f32_32x32x16_bf16(kf[ks], qf[1][ks], c1, 0, 0, 0);
            }
            __builtin_amdgcn_s_setprio(0);
#pragma unroll
            for (int r = 0; r < 16; r += 2) {
                float p0 = fast_exp2(c0[r]);
                float p1 = fast_exp2(c0[r + 1]);
                lsum0 += p0 + p1;
                pa0[2 * nt + (r >> 3)].u[(r & 7) >> 1] = pack2bf(p0, p1);
            }
#pragma unroll
            for (int r = 0; r < 16; r += 2) {
                float p0 = fast_exp2(c1[r]);
                float p1 = fast_exp2(c1[r + 1]);
                lsum1 += p0 + p1;
                pa1[2 * nt + (r >> 3)].u[(r & 7) >> 1] = pack2bf(p0, p1);
            }
        }

        // PV per e-half: JIT vf loads shared by both q-groups
#pragma unroll
        for (int ent = 0; ent < 2; ent++) {
            int rowb = (ent * 32 + l32) * 8;
            short8 vf[4];
#pragma unroll
            for (int ks = 0; ks < 4; ks++)
                vf[ks] = *(const short8*)(Vcur + (size_t)(rowb + ((ks * 2 + half) ^ sw)) * 8);
            __builtin_amdgcn_s_setprio(1);
#pragma unroll
            for (int ks = 0; ks < 4; ks++) {
                acc[ent][0] = __builtin_amdgcn_mfma_f32_32x32x16_bf16(pa0[ks].s8, vf[ks], acc[ent][0], 0, 0, 0);
                acc[ent][1] = __builtin_amdgcn_mfma_f32_32x32x16_bf16(pa1[ks].s8, vf[ks], acc[ent][1], 0, 0, 0);
            }
            __builtin_amdgcn_s_setprio(0);
        }

        cur = (cur == 2) ? 0 : cur + 1;
    }

    // denominators: lanes l and l^32 hold same q-row's two key-halves
    float den0 = lsum0 + __shfl_xor(lsum0, 32);
    float den1 = lsum1 + __shfl_xor(lsum1, 32);
    float inv0 = 1.0f / den0;
    float inv1 = 1.0f / den1;

    int b_ = bh / 12, h = bh % 12;
#pragma unroll
    for (int qg = 0; qg < 2; qg++)
#pragma unroll
        for (int ent = 0; ent < 2; ent++)
#pragma unroll
            for (int r = 0; r < 16; r++) {
                int qloc = (r & 3) + 8 * (r >> 2) + 4 * half;
                float invq = __shfl(qg ? inv1 : inv0, qloc);
                int q = qbase + qg * 32 + qloc;
                int e = ent * 32 + l32;
                Ctx[((size_t)(b_ * 2048 + q)) * 768 + h * 64 + e] = f2bf(acc[ent][qg][r] * invq);
            }
}

// ---------------- proj GEMM: out[8192,768] = Ctx @ W2^T + b, fp32 out ----------------
// Tile 64(M) x 128(N): 768 blocks = exactly 3/CU. XCD remap: XCD c owns M-rows [16c,16c+16).
__global__ __launch_bounds__(256) void gemm_out(
    const short* __restrict__ Ctx, const short* __restrict__ W,
    const float* __restrict__ bias, float* __restrict__ out)
{
    __shared__ short As[64 * 32];
    __shared__ short Bs[128 * 32];
    int tid = threadIdx.x;
    int w = tid >> 6, l = tid & 63;
    int lane16 = l & 15, quad = l >> 4;
    int wm = w & 1, wn = w >> 1;

    int fid = blockIdx.x + 6 * blockIdx.y;    // 0..767
    int c = fid & 7, s = fid >> 3;            // s in 0..95
    int my = c * 16 + s / 6;                  // 0..127
    int nx = s % 6;                           // 0..5
    int m0 = my * 64, n0 = nx * 128;

    floatx4 acc[2][4] = {};

    int srow = tid >> 2;        // 0..63
    int scol = (tid & 3) * 8;
    const short* Xg = Ctx + (size_t)(m0 + srow) * KDIM + scol;
    const short* Wg = W + (size_t)(n0 + srow) * KDIM + scol;
    short* AsW = As + (w * 16) * 32;
    short* BsW = Bs + (w * 16) * 32;

    for (int kb = 0; kb < KDIM; kb += 32) {
        __syncthreads();
        async16(Xg + kb,             AsW);
        async16(Wg + kb,             BsW);
        async16(Wg + kb + 64 * KDIM, BsW + 64 * 32);
        __syncthreads();
        short8 a[2], b[4];
#pragma unroll
        for (int mt = 0; mt < 2; mt++) a[mt] = *(const short8*)(As + (wm * 32 + mt * 16 + lane16) * 32 + quad * 8);
#pragma unroll
        for (int nt = 0; nt < 4; nt++) b[nt] = *(const short8*)(Bs + (wn * 64 + nt * 16 + lane16) * 32 + quad * 8);
#pragma unroll
        for (int mt = 0; mt < 2; mt++)
#pragma unroll
            for (int nt = 0; nt < 4; nt++)
                acc[mt][nt] = __builtin_amdgcn_mfma_f32_16x16x32_bf16(a[mt], b[nt], acc[mt][nt], 0, 0, 0);
    }

#pragma unroll
    for (int mt = 0; mt < 2; mt++) {
        int row = m0 + wm * 32 + mt * 16 + quad * 4;
#pragma unroll
        for (int nt = 0; nt < 4; nt++) {
            int col = n0 + wn * 64 + nt * 16 + lane16;
            float bv = bias[col];
#pragma unroll
            for (int r = 0; r < 4; r++)
                out[(size_t)(row + r) * 768 + col] = acc[mt][nt][r] + bv;
        }
    }
}

extern "C" void kernel_launch(void* const* d_in, const int* in_sizes, int n_in,
                              void* d_out, int out_size, void* d_ws, size_t ws_size,
                              hipStream_t stream) {
    const float* hs     = (const float*)d_in[0];
    const float* qkv_w  = (const float*)d_in[1];
    const float* qkv_b  = (const float*)d_in[2];
    const float* proj_w = (const float*)d_in[3];
    const float* proj_b = (const float*)d_in[4];
    float* out = (float*)d_out;

    short* Xb  = (short*)d_ws;                     // 8192*768
    short* W1b = Xb  + (size_t)8192 * 768;         // 2304*768
    short* W2b = W1b + (size_t)2304 * 768;         // 768*768
    short* Qb  = W2b + (size_t)768 * 768;          // 48*2048*64
    short* Kb  = Qb  + (size_t)8192 * 768;
    short* Vt  = Kb  + (size_t)8192 * 768;         // [bh][e][2048] sigma-ordered, written by gemm_qkv
    short* Ctx = Vt  + (size_t)8192 * 768;         // 8192*768

    int ntot = (N1 + N2 + N3) / 4;
    cvt_all<<<(ntot + 255) / 256, 256, 0, stream>>>(hs, qkv_w, proj_w, Xb, W1b, W2b);

    gemm_qkv<<<dim3(18, 64), 256, 0, stream>>>(Xb, W1b, qkv_b, Qb, Kb, Vt);
    attn<<<dim3(16, 48), 128, 0, stream>>>(Qb, Kb, Vt, Ctx);
    gemm_out<<<dim3(6, 128), 256, 0, stream>>>(Ctx, W2b, proj_b, out);
}

// Round 9
// 223.813 us; speedup vs baseline: 1.2409x; 1.2409x over previous
//
#include <hip/hip_runtime.h>
#include <hip/hip_bf16.h>

using short8   = __attribute__((ext_vector_type(8))) short;
using floatx4  = __attribute__((ext_vector_type(4))) float;
using floatx16 = __attribute__((ext_vector_type(16))) float;

#define KDIM 768
#define QSCALE 0.18033688011112042f   // 0.125 * log2(e)
#define N1 (8192 * 768)
#define N2 (2304 * 768)
#define N3 (768 * 768)

__device__ __forceinline__ short f2bf(float f) {
    union { float f; unsigned u; } v; v.f = f;
    unsigned r = v.u + 0x7fffu + ((v.u >> 16) & 1u);
    return (short)(r >> 16);
}

__device__ __forceinline__ unsigned pack2bf(float a, float b) {
    __hip_bfloat162 h = __float22bfloat162_rn(float2{a, b});
    union { __hip_bfloat162 h; unsigned u; } c; c.h = h;
    return c.u;
}

__device__ __forceinline__ float fast_exp2(float x) {
#if __has_builtin(__builtin_amdgcn_exp2f)
    return __builtin_amdgcn_exp2f(x);
#else
    return exp2f(x);
#endif
}

__device__ __forceinline__ void async16(const void* g, void* l) {
    __builtin_amdgcn_global_load_lds((const __attribute__((address_space(1))) void*)g,
                                     (__attribute__((address_space(3))) void*)l, 16, 0, 0);
}

// ---------------- fused fp32 -> bf16 convert for all three inputs ----------------
__global__ void cvt_all(const float* __restrict__ a, const float* __restrict__ b,
                        const float* __restrict__ c, short* __restrict__ oa,
                        short* __restrict__ ob, short* __restrict__ oc) {
    int i = (blockIdx.x * blockDim.x + threadIdx.x) * 4;
    const float* src; short* dst;
    if (i < N1)            { src = a + i;            dst = oa + i; }
    else if (i < N1 + N2)  { src = b + (i - N1);     dst = ob + (i - N1); }
    else if (i < N1+N2+N3) { src = c + (i - N1 - N2); dst = oc + (i - N1 - N2); }
    else return;
    float4 v = *(const float4*)src;
    short4 o;
    o.x = f2bf(v.x); o.y = f2bf(v.y); o.z = f2bf(v.z); o.w = f2bf(v.w);
    *(short4*)dst = o;
}

// ---------------- QKV GEMM: C[8192,2304] = X @ W^T, scatter to Q/K/V [bh][s][64] ----------------
// BK=64 (half the barrier/drain pairs of BK=32), XOR-chunk-swizzled LDS (pre-swizzled
// global source + swizzled read; spreads each b128 read across all 32 banks).
// XCD remap, nx-OUTER within XCD: working set = one 196 KB W-panel + 1.5 MB X-slice << 4 MB L2.
// Epilogue: C-tile via LDS, coalesced 16B/lane write-back (r7).
__global__ __launch_bounds__(256) void gemm_qkv(
    const short* __restrict__ X, const short* __restrict__ W,
    const float* __restrict__ bias,
    short* __restrict__ Qb, short* __restrict__ Kb, short* __restrict__ Vb)
{
    __shared__ short Smem[128 * 144];          // 36 KB: As/Bs (2x16 KB) in K-loop, C-tile after
    short* As = Smem;                          // 128*64
    short* Bs = Smem + 128 * 64;               // 128*64
    int tid = threadIdx.x;
    int w = tid >> 6, l = tid & 63;
    int lane16 = l & 15, quad = l >> 4;
    int wm = w & 1, wn = w >> 1;

    int fid = blockIdx.x + 18 * blockIdx.y;   // 0..1151, dispatch order
    int c = fid & 7, s = fid >> 3;            // s in 0..143
    int nx = s >> 3;                          // 0..17  (outer: consecutive blocks share W-panel)
    int my = c * 8 + (s & 7);                 // 0..63
    int m0 = my * 128, n0 = nx * 128;

    floatx4 acc[4][4] = {};

    // staging: lane l covers row 8w+(l>>3) (+32 per call), source chunk pre-swizzled
    int srow = 8 * w + (l >> 3);
    int g = ((l & 7) ^ (l >> 3)) * 8;
    const short* Xg = X + (size_t)(m0 + srow) * KDIM + g;
    const short* Wg = W + (size_t)(n0 + srow) * KDIM + g;
    int swr = lane16 & 7;                     // read-side swizzle term (row&7)

    for (int kb = 0; kb < KDIM; kb += 64) {
        __syncthreads();
#pragma unroll
        for (int j = 0; j < 4; j++) {
            async16(Xg + (size_t)j * 32 * KDIM + kb, As + (j * 32 + 8 * w) * 64);
            async16(Wg + (size_t)j * 32 * KDIM + kb, Bs + (j * 32 + 8 * w) * 64);
        }
        __syncthreads();
#pragma unroll
        for (int ks = 0; ks < 2; ks++) {
            short8 a[4], b[4];
#pragma unroll
            for (int mt = 0; mt < 4; mt++)
                a[mt] = *(const short8*)(As + (wm * 64 + mt * 16 + lane16) * 64 + ((ks * 4 + quad) ^ swr) * 8);
#pragma unroll
            for (int nt = 0; nt < 4; nt++)
                b[nt] = *(const short8*)(Bs + (wn * 64 + nt * 16 + lane16) * 64 + ((ks * 4 + quad) ^ swr) * 8);
#pragma unroll
            for (int mt = 0; mt < 4; mt++)
#pragma unroll
                for (int nt = 0; nt < 4; nt++)
                    acc[mt][nt] = __builtin_amdgcn_mfma_f32_16x16x32_bf16(a[mt], b[nt], acc[mt][nt], 0, 0, 0);
        }
    }

    // ---- epilogue: acc -> LDS (bias + scale + bf16) -> coalesced global writes ----
    int qkv = nx / 6;                          // whole block is one of Q/K/V
    float sc = (qkv == 0) ? (float)QSCALE : 1.0f;
    short* dst = (qkv == 0) ? Qb : ((qkv == 1) ? Kb : Vb);
    int h0 = (nx - qkv * 6) * 2;               // first of the 2 heads this block covers
    int b_ = m0 >> 11, s0 = m0 & 2047;

    __syncthreads();                           // all MFMA reads of As/Bs complete
#pragma unroll
    for (int mt = 0; mt < 4; mt++) {
        int rowl = wm * 64 + mt * 16 + quad * 4;
#pragma unroll
        for (int nt = 0; nt < 4; nt++) {
            int coll = wn * 64 + nt * 16 + lane16;
            float bv = bias[n0 + coll];
#pragma unroll
            for (int r = 0; r < 4; r++)
                Smem[(rowl + r) * 144 + coll] = f2bf((acc[mt][nt][r] + bv) * sc);
        }
    }
    __syncthreads();
#pragma unroll
    for (int i = 0; i < 8; i++) {
        int slot = i * 256 + tid;
        int ch = slot >> 10;
        int rem2 = slot & 1023;
        int s_loc = rem2 >> 3, e8 = rem2 & 7;
        short8 v = *(const short8*)(Smem + s_loc * 144 + ch * 64 + e8 * 8);
        *(short8*)(dst + (((size_t)(b_ * 12 + h0 + ch)) * 2048 + s0 + s_loc) * 64 + e8 * 8) = v;
    }
}

// ---------------- V transpose + sigma key-permute: Vb [bh][s][64] -> Vt [bh][e][64-key tiles] ----------------
__global__ __launch_bounds__(256) void transpose_v(
    const short* __restrict__ Vb, short* __restrict__ Vt)
{
    __shared__ short T[64 * 66];
    int tid = threadIdx.x;
    int s0 = blockIdx.x * 64, bh = blockIdx.y;
    const short* src = Vb + (size_t)bh * 2048 * 64;
    short* dst = Vt + (size_t)bh * 64 * 2048;

#pragma unroll
    for (int i = 0; i < 2; i++) {
        int slot = i * 256 + tid;
        int s_loc = slot >> 3, ec = slot & 7;
        short8 v = *(const short8*)(src + (size_t)(s0 + s_loc) * 64 + ec * 8);
        *(short8*)(T + s_loc * 66 + ec * 8) = v;
    }
    __syncthreads();
#pragma unroll
    for (int i = 0; i < 2; i++) {
        int slot = i * 256 + tid;
        int e_loc = slot >> 3, sc = slot & 7;
        short8 o;
#pragma unroll
        for (int j = 0; j < 8; j++) {
            int p = sc * 8 + j;
            int kp = (p & 0x33) | ((p & 4) << 1) | ((p & 8) >> 1);   // sigma: swap bits 2,3
            o[j] = T[kp * 66 + e_loc];
        }
        *(short8*)(dst + (size_t)e_loc * 2048 + s0 + sc * 8) = o;
    }
}

// ---------------- flash attention (r5 kernel verbatim, best measured 72.1-72.6 us) ----------------
// grid (16,48), 4 waves, 32 q-rows/wave (occupancy-optimal: 3072 waves = 3/SIMD),
// triple-buffered K/V, depth-2 prefetch, one s_barrier + counted vmcnt(4) per tile,
// XCD-aware remap (FETCH 104->18.5 MB), setprio around MFMA clusters.
__global__ __launch_bounds__(256, 3) void attn(
    const short* __restrict__ Qb, const short* __restrict__ Kb,
    const short* __restrict__ Vt, short* __restrict__ Ctx)
{
    __shared__ short Ks[3][512 * 8];
    __shared__ short Vs[3][512 * 8];
    int tid = threadIdx.x, w = tid >> 6, l = tid & 63;
    int l32 = l & 31, half = l >> 5;

    int fid = blockIdx.x + (blockIdx.y << 4);   // 0..767, dispatch order
    int c = fid & 7, sfl = fid >> 3;            // sfl in 0..95
    int bh = c * 6 + (sfl >> 4);                // XCD c owns 6 heads
    int qt = sfl & 15;

    const short* Qh  = Qb + (size_t)bh * 2048 * 64;
    const short* Kh  = Kb + (size_t)bh * 2048 * 64;
    const short* Vth = Vt + (size_t)bh * 64 * 2048;
    int qbase = qt * 128 + w * 32;

    const short* kSrc[2];
    const short* vSrc[2];
    int dOff[2];
#pragma unroll
    for (int i = 0; i < 2; i++) {
        int slot = i * 256 + tid;
        int row = slot >> 3;
        int g = (slot & 7) ^ (row & 7);
        kSrc[i] = Kh + (size_t)row * 64 + g * 8;
        vSrc[i] = Vth + (size_t)row * 2048 + g * 8;
        dOff[i] = (i * 256 + w * 64) * 8;
    }

    short8 qf[4];
#pragma unroll
    for (int ks = 0; ks < 4; ks++)
        qf[ks] = *(const short8*)(Qh + (size_t)(qbase + l32) * 64 + ks * 16 + half * 8);

#pragma unroll
    for (int i = 0; i < 2; i++) {
        async16(kSrc[i],        &Ks[0][0] + dOff[i]);
        async16(vSrc[i],        &Vs[0][0] + dOff[i]);
    }
#pragma unroll
    for (int i = 0; i < 2; i++) {
        async16(kSrc[i] + 4096, &Ks[1][0] + dOff[i]);
        async16(vSrc[i] + 64,   &Vs[1][0] + dOff[i]);
    }

    float lsum = 0.f;
    floatx16 acc[2] = {};
    int sw = l32 & 7;

    int cur = 0;
    for (int kt = 0; kt < 32; kt++) {
        if (kt < 31) { asm volatile("s_waitcnt vmcnt(4)" ::: "memory"); }
        else         { asm volatile("s_waitcnt vmcnt(0)" ::: "memory"); }
        __builtin_amdgcn_s_barrier();

        int pf = kt + 2;
        if (pf < 32) {
            int pb = cur >= 1 ? cur - 1 : cur + 2;
#pragma unroll
            for (int i = 0; i < 2; i++) {
                async16(kSrc[i] + (size_t)pf * 4096, &Ks[pb][0] + dOff[i]);
                async16(vSrc[i] + (size_t)pf * 64,   &Vs[pb][0] + dOff[i]);
            }
        }

        const short* Kcur = &Ks[cur][0];
        const short* Vcur = &Vs[cur][0];

        floatx16 s[2];
        __builtin_amdgcn_s_setprio(1);
#pragma unroll
        for (int nt = 0; nt < 2; nt++) {
            floatx16 cacc = {};
            int rowb = (nt * 32 + l32) * 8;
#pragma unroll
            for (int ks = 0; ks < 4; ks++) {
                short8 kf = *(const short8*)(Kcur + (size_t)(rowb + ((ks * 2 + half) ^ sw)) * 8);
                cacc = __builtin_amdgcn_mfma_f32_32x32x16_bf16(kf, qf[ks], cacc, 0, 0, 0);
            }
            s[nt] = cacc;
        }
        __builtin_amdgcn_s_setprio(0);

        union { short8 s8; unsigned u[4]; } pa[4];
#pragma unroll
        for (int nt = 0; nt < 2; nt++)
#pragma unroll
            for (int r = 0; r < 16; r += 2) {
                float p0 = fast_exp2(s[nt][r]);
                float p1 = fast_exp2(s[nt][r + 1]);
                lsum += p0 + p1;
                pa[2 * nt + (r >> 3)].u[(r & 7) >> 1] = pack2bf(p0, p1);
            }

        __builtin_amdgcn_s_setprio(1);
#pragma unroll
        for (int nt = 0; nt < 2; nt++) {
            int rowb = (nt * 32 + l32) * 8;
#pragma unroll
            for (int ks = 0; ks < 4; ks++) {
                short8 vf = *(const short8*)(Vcur + (size_t)(rowb + ((ks * 2 + half) ^ sw)) * 8);
                acc[nt] = __builtin_amdgcn_mfma_f32_32x32x16_bf16(pa[ks].s8, vf, acc[nt], 0, 0, 0);
            }
        }
        __builtin_amdgcn_s_setprio(0);

        cur = (cur == 2) ? 0 : cur + 1;
    }

    float denom = lsum + __shfl_xor(lsum, 32);
    float inv_self = 1.0f / denom;

    int b_ = bh / 12, h = bh % 12;
#pragma unroll
    for (int nt = 0; nt < 2; nt++)
#pragma unroll
        for (int r = 0; r < 16; r++) {
            int qloc = (r & 3) + 8 * (r >> 2) + 4 * half;
            float invq = __shfl(inv_self, qloc);
            int q = qbase + qloc;
            int e = nt * 32 + l32;
            Ctx[((size_t)(b_ * 2048 + q)) * 768 + h * 64 + e] = f2bf(acc[nt][r] * invq);
        }
}

// ---------------- proj GEMM: out[8192,768] = Ctx @ W2^T + b, fp32 out ----------------
// BK=64 + swizzle (same scheme as gemm_qkv). Tile 64x128, 768 blocks = 3/CU, XCD remap.
__global__ __launch_bounds__(256) void gemm_out(
    const short* __restrict__ Ctx, const short* __restrict__ W,
    const float* __restrict__ bias, float* __restrict__ out)
{
    __shared__ short As[64 * 64];
    __shared__ short Bs[128 * 64];
    int tid = threadIdx.x;
    int w = tid >> 6, l = tid & 63;
    int lane16 = l & 15, quad = l >> 4;
    int wm = w & 1, wn = w >> 1;

    int fid = blockIdx.x + 6 * blockIdx.y;    // 0..767
    int c = fid & 7, s = fid >> 3;            // s in 0..95
    int my = c * 16 + s / 6;                  // 0..127
    int nx = s % 6;                           // 0..5
    int m0 = my * 64, n0 = nx * 128;

    floatx4 acc[2][4] = {};

    int srow = 8 * w + (l >> 3);
    int g = ((l & 7) ^ (l >> 3)) * 8;
    const short* Xg = Ctx + (size_t)(m0 + srow) * KDIM + g;
    const short* Wg = W + (size_t)(n0 + srow) * KDIM + g;
    int swr = lane16 & 7;

    for (int kb = 0; kb < KDIM; kb += 64) {
        __syncthreads();
#pragma unroll
        for (int j = 0; j < 2; j++)
            async16(Xg + (size_t)j * 32 * KDIM + kb, As + (j * 32 + 8 * w) * 64);
#pragma unroll
        for (int j = 0; j < 4; j++)
            async16(Wg + (size_t)j * 32 * KDIM + kb, Bs + (j * 32 + 8 * w) * 64);
        __syncthreads();
#pragma unroll
        for (int ks = 0; ks < 2; ks++) {
            short8 a[2], b[4];
#pragma unroll
            for (int mt = 0; mt < 2; mt++)
                a[mt] = *(const short8*)(As + (wm * 32 + mt * 16 + lane16) * 64 + ((ks * 4 + quad) ^ swr) * 8);
#pragma unroll
            for (int nt = 0; nt < 4; nt++)
                b[nt] = *(const short8*)(Bs + (wn * 64 + nt * 16 + lane16) * 64 + ((ks * 4 + quad) ^ swr) * 8);
#pragma unroll
            for (int mt = 0; mt < 2; mt++)
#pragma unroll
                for (int nt = 0; nt < 4; nt++)
                    acc[mt][nt] = __builtin_amdgcn_mfma_f32_16x16x32_bf16(a[mt], b[nt], acc[mt][nt], 0, 0, 0);
        }
    }

#pragma unroll
    for (int mt = 0; mt < 2; mt++) {
        int row = m0 + wm * 32 + mt * 16 + quad * 4;
#pragma unroll
        for (int nt = 0; nt < 4; nt++) {
            int col = n0 + wn * 64 + nt * 16 + lane16;
            float bv = bias[col];
#pragma unroll
            for (int r = 0; r < 4; r++)
                out[(size_t)(row + r) * 768 + col] = acc[mt][nt][r] + bv;
        }
    }
}

extern "C" void kernel_launch(void* const* d_in, const int* in_sizes, int n_in,
                              void* d_out, int out_size, void* d_ws, size_t ws_size,
                              hipStream_t stream) {
    const float* hs     = (const float*)d_in[0];
    const float* qkv_w  = (const float*)d_in[1];
    const float* qkv_b  = (const float*)d_in[2];
    const float* proj_w = (const float*)d_in[3];
    const float* proj_b = (const float*)d_in[4];
    float* out = (float*)d_out;

    short* Xb  = (short*)d_ws;                     // 8192*768 (dead after gemm_qkv; reused as Vt)
    short* W1b = Xb  + (size_t)8192 * 768;         // 2304*768
    short* W2b = W1b + (size_t)2304 * 768;         // 768*768
    short* Qb  = W2b + (size_t)768 * 768;          // 48*2048*64
    short* Kb  = Qb  + (size_t)8192 * 768;
    short* Vb  = Kb  + (size_t)8192 * 768;
    short* Ctx = Vb  + (size_t)8192 * 768;         // 8192*768
    short* Vt  = Xb;                               // [bh][64][2048] sigma-ordered, overlays dead Xb

    int ntot = (N1 + N2 + N3) / 4;
    cvt_all<<<(ntot + 255) / 256, 256, 0, stream>>>(hs, qkv_w, proj_w, Xb, W1b, W2b);

    gemm_qkv<<<dim3(18, 64), 256, 0, stream>>>(Xb, W1b, qkv_b, Qb, Kb, Vb);
    transpose_v<<<dim3(32, 48), 256, 0, stream>>>(Vb, Vt);
    attn<<<dim3(16, 48), 256, 0, stream>>>(Qb, Kb, Vt, Ctx);
    gemm_out<<<dim3(6, 128), 256, 0, stream>>>(Ctx, W2b, proj_b, out);
}

// Round 10
// 218.815 us; speedup vs baseline: 1.2693x; 1.0228x over previous
//
#include <hip/hip_runtime.h>
#include <hip/hip_bf16.h>

using short8   = __attribute__((ext_vector_type(8))) short;
using floatx4  = __attribute__((ext_vector_type(4))) float;
using floatx16 = __attribute__((ext_vector_type(16))) float;

#define KDIM 768
#define QSCALE 0.18033688011112042f   // 0.125 * log2(e)
#define N1 (8192 * 768)
#define N2 (2304 * 768)
#define N3 (768 * 768)

__device__ __forceinline__ short f2bf(float f) {
    union { float f; unsigned u; } v; v.f = f;
    unsigned r = v.u + 0x7fffu + ((v.u >> 16) & 1u);
    return (short)(r >> 16);
}

__device__ __forceinline__ unsigned pack2bf(float a, float b) {
    __hip_bfloat162 h = __float22bfloat162_rn(float2{a, b});
    union { __hip_bfloat162 h; unsigned u; } c; c.h = h;
    return c.u;
}

__device__ __forceinline__ float fast_exp2(float x) {
#if __has_builtin(__builtin_amdgcn_exp2f)
    return __builtin_amdgcn_exp2f(x);
#else
    return exp2f(x);
#endif
}

__device__ __forceinline__ void async16(const void* g, void* l) {
    __builtin_amdgcn_global_load_lds((const __attribute__((address_space(1))) void*)g,
                                     (__attribute__((address_space(3))) void*)l, 16, 0, 0);
}

// ---------------- fused fp32 -> bf16 convert, grid-stride at 2048 blocks (G11) ----------------
__global__ __launch_bounds__(256) void cvt_all(
    const float* __restrict__ a, const float* __restrict__ b,
    const float* __restrict__ c, short* __restrict__ oa,
    short* __restrict__ ob, short* __restrict__ oc) {
    const int ntot = (N1 + N2 + N3) / 4;
    for (int t = blockIdx.x * blockDim.x + threadIdx.x; t < ntot; t += gridDim.x * blockDim.x) {
        int i = t * 4;
        const float* src; short* dst;
        if (i < N1)            { src = a + i;             dst = oa + i; }
        else if (i < N1 + N2)  { src = b + (i - N1);      dst = ob + (i - N1); }
        else                   { src = c + (i - N1 - N2); dst = oc + (i - N1 - N2); }
        float4 v = *(const float4*)src;
        short4 o;
        o.x = f2bf(v.x); o.y = f2bf(v.y); o.z = f2bf(v.z); o.w = f2bf(v.w);
        *(short4*)dst = o;
    }
}

// ---------------- QKV GEMM: C[8192,2304] = X @ W^T, scatter to Q/K/V [bh][s][64] ----------------
// r7 form (best measured): BK=32, XCD remap (XCD c owns M-rows [8c,8c+8)),
// LDS-staged coalesced epilogue (C-tile -> 16B/lane write-back).
__global__ __launch_bounds__(256) void gemm_qkv(
    const short* __restrict__ X, const short* __restrict__ W,
    const float* __restrict__ bias,
    short* __restrict__ Qb, short* __restrict__ Kb, short* __restrict__ Vb)
{
    __shared__ short Smem[128 * 144];          // 36 KB: As/Bs (16 KB) during K-loop, C-tile after
    short* As = Smem;                          // 128*32
    short* Bs = Smem + 128 * 32;               // 128*32
    int tid = threadIdx.x;
    int w = tid >> 6, l = tid & 63;
    int lane16 = l & 15, quad = l >> 4;
    int wm = w & 1, wn = w >> 1;

    int fid = blockIdx.x + 18 * blockIdx.y;   // 0..1151, dispatch order
    int c = fid & 7, s = fid >> 3;            // s in 0..143
    int my = c * 8 + s / 18;                  // 0..63
    int nx = s % 18;                          // 0..17
    int m0 = my * 128, n0 = nx * 128;

    floatx4 acc[4][4] = {};

    int srow = w * 32 + (l >> 2);
    int scol = (l & 3) * 8;
    const short* Xg = X + (size_t)(m0 + srow) * KDIM + scol;
    const short* Wg = W + (size_t)(n0 + srow) * KDIM + scol;
    short* AsW = As + (w * 32) * 32;
    short* BsW = Bs + (w * 32) * 32;

    for (int kb = 0; kb < KDIM; kb += 32) {
        __syncthreads();
        async16(Xg + kb,              AsW);
        async16(Xg + kb + 16 * KDIM,  AsW + 16 * 32);
        async16(Wg + kb,              BsW);
        async16(Wg + kb + 16 * KDIM,  BsW + 16 * 32);
        __syncthreads();
        short8 a[4], b[4];
#pragma unroll
        for (int mt = 0; mt < 4; mt++) a[mt] = *(const short8*)(As + (wm * 64 + mt * 16 + lane16) * 32 + quad * 8);
#pragma unroll
        for (int nt = 0; nt < 4; nt++) b[nt] = *(const short8*)(Bs + (wn * 64 + nt * 16 + lane16) * 32 + quad * 8);
#pragma unroll
        for (int mt = 0; mt < 4; mt++)
#pragma unroll
            for (int nt = 0; nt < 4; nt++)
                acc[mt][nt] = __builtin_amdgcn_mfma_f32_16x16x32_bf16(a[mt], b[nt], acc[mt][nt], 0, 0, 0);
    }

    // ---- epilogue: acc -> LDS (bias + scale + bf16) -> coalesced global writes ----
    int qkv = nx / 6;                          // whole block is one of Q/K/V
    float sc = (qkv == 0) ? (float)QSCALE : 1.0f;
    short* dst = (qkv == 0) ? Qb : ((qkv == 1) ? Kb : Vb);
    int h0 = (nx - qkv * 6) * 2;               // first of the 2 heads this block covers
    int b_ = m0 >> 11, s0 = m0 & 2047;

    __syncthreads();                           // all MFMA reads of As/Bs complete
#pragma unroll
    for (int mt = 0; mt < 4; mt++) {
        int rowl = wm * 64 + mt * 16 + quad * 4;
#pragma unroll
        for (int nt = 0; nt < 4; nt++) {
            int coll = wn * 64 + nt * 16 + lane16;
            float bv = bias[n0 + coll];
#pragma unroll
            for (int r = 0; r < 4; r++)
                Smem[(rowl + r) * 144 + coll] = f2bf((acc[mt][nt][r] + bv) * sc);
        }
    }
    __syncthreads();
#pragma unroll
    for (int i = 0; i < 8; i++) {
        int slot = i * 256 + tid;
        int ch = slot >> 10;
        int rem2 = slot & 1023;
        int s_loc = rem2 >> 3, e8 = rem2 & 7;
        short8 v = *(const short8*)(Smem + s_loc * 144 + ch * 64 + e8 * 8);
        *(short8*)(dst + (((size_t)(b_ * 12 + h0 + ch)) * 2048 + s0 + s_loc) * 64 + e8 * 8) = v;
    }
}

// ---------------- V transpose + sigma key-permute: Vb [bh][s][64] -> Vt [bh][e][64-key tiles] ----------------
__global__ __launch_bounds__(256) void transpose_v(
    const short* __restrict__ Vb, short* __restrict__ Vt)
{
    __shared__ short T[64 * 66];
    int tid = threadIdx.x;
    int s0 = blockIdx.x * 64, bh = blockIdx.y;
    const short* src = Vb + (size_t)bh * 2048 * 64;
    short* dst = Vt + (size_t)bh * 64 * 2048;

#pragma unroll
    for (int i = 0; i < 2; i++) {
        int slot = i * 256 + tid;
        int s_loc = slot >> 3, ec = slot & 7;
        short8 v = *(const short8*)(src + (size_t)(s0 + s_loc) * 64 + ec * 8);
        *(short8*)(T + s_loc * 66 + ec * 8) = v;
    }
    __syncthreads();
#pragma unroll
    for (int i = 0; i < 2; i++) {
        int slot = i * 256 + tid;
        int e_loc = slot >> 3, sc = slot & 7;
        short8 o;
#pragma unroll
        for (int j = 0; j < 8; j++) {
            int p = sc * 8 + j;
            int kp = (p & 0x33) | ((p & 4) << 1) | ((p & 8) >> 1);   // sigma: swap bits 2,3
            o[j] = T[kp * 66 + e_loc];
        }
        *(short8*)(dst + (size_t)e_loc * 2048 + s0 + sc * 8) = o;
    }
}

// ---------------- flash attention (r5/r7 kernel verbatim, best measured 72.1-72.6 us) ----------------
// grid (16,48), 4 waves, 32 q-rows/wave (occupancy-optimal: 3072 waves = 3/SIMD),
// triple-buffered K/V, depth-2 prefetch, one s_barrier + counted vmcnt(4) per tile,
// XCD-aware remap (FETCH 104->18.5 MB), setprio around MFMA clusters.
__global__ __launch_bounds__(256, 3) void attn(
    const short* __restrict__ Qb, const short* __restrict__ Kb,
    const short* __restrict__ Vt, short* __restrict__ Ctx)
{
    __shared__ short Ks[3][512 * 8];
    __shared__ short Vs[3][512 * 8];
    int tid = threadIdx.x, w = tid >> 6, l = tid & 63;
    int l32 = l & 31, half = l >> 5;

    int fid = blockIdx.x + (blockIdx.y << 4);   // 0..767, dispatch order
    int c = fid & 7, sfl = fid >> 3;            // sfl in 0..95
    int bh = c * 6 + (sfl >> 4);                // XCD c owns 6 heads
    int qt = sfl & 15;

    const short* Qh  = Qb + (size_t)bh * 2048 * 64;
    const short* Kh  = Kb + (size_t)bh * 2048 * 64;
    const short* Vth = Vt + (size_t)bh * 64 * 2048;
    int qbase = qt * 128 + w * 32;

    const short* kSrc[2];
    const short* vSrc[2];
    int dOff[2];
#pragma unroll
    for (int i = 0; i < 2; i++) {
        int slot = i * 256 + tid;
        int row = slot >> 3;
        int g = (slot & 7) ^ (row & 7);
        kSrc[i] = Kh + (size_t)row * 64 + g * 8;
        vSrc[i] = Vth + (size_t)row * 2048 + g * 8;
        dOff[i] = (i * 256 + w * 64) * 8;
    }

    short8 qf[4];
#pragma unroll
    for (int ks = 0; ks < 4; ks++)
        qf[ks] = *(const short8*)(Qh + (size_t)(qbase + l32) * 64 + ks * 16 + half * 8);

#pragma unroll
    for (int i = 0; i < 2; i++) {
        async16(kSrc[i],        &Ks[0][0] + dOff[i]);
        async16(vSrc[i],        &Vs[0][0] + dOff[i]);
    }
#pragma unroll
    for (int i = 0; i < 2; i++) {
        async16(kSrc[i] + 4096, &Ks[1][0] + dOff[i]);
        async16(vSrc[i] + 64,   &Vs[1][0] + dOff[i]);
    }

    float lsum = 0.f;
    floatx16 acc[2] = {};
    int sw = l32 & 7;

    int cur = 0;
    for (int kt = 0; kt < 32; kt++) {
        if (kt < 31) { asm volatile("s_waitcnt vmcnt(4)" ::: "memory"); }
        else         { asm volatile("s_waitcnt vmcnt(0)" ::: "memory"); }
        __builtin_amdgcn_s_barrier();

        int pf = kt + 2;
        if (pf < 32) {
            int pb = cur >= 1 ? cur - 1 : cur + 2;
#pragma unroll
            for (int i = 0; i < 2; i++) {
                async16(kSrc[i] + (size_t)pf * 4096, &Ks[pb][0] + dOff[i]);
                async16(vSrc[i] + (size_t)pf * 64,   &Vs[pb][0] + dOff[i]);
            }
        }

        const short* Kcur = &Ks[cur][0];
        const short* Vcur = &Vs[cur][0];

        floatx16 s[2];
        __builtin_amdgcn_s_setprio(1);
#pragma unroll
        for (int nt = 0; nt < 2; nt++) {
            floatx16 cacc = {};
            int rowb = (nt * 32 + l32) * 8;
#pragma unroll
            for (int ks = 0; ks < 4; ks++) {
                short8 kf = *(const short8*)(Kcur + (size_t)(rowb + ((ks * 2 + half) ^ sw)) * 8);
                cacc = __builtin_amdgcn_mfma_f32_32x32x16_bf16(kf, qf[ks], cacc, 0, 0, 0);
            }
            s[nt] = cacc;
        }
        __builtin_amdgcn_s_setprio(0);

        union { short8 s8; unsigned u[4]; } pa[4];
#pragma unroll
        for (int nt = 0; nt < 2; nt++)
#pragma unroll
            for (int r = 0; r < 16; r += 2) {
                float p0 = fast_exp2(s[nt][r]);
                float p1 = fast_exp2(s[nt][r + 1]);
                lsum += p0 + p1;
                pa[2 * nt + (r >> 3)].u[(r & 7) >> 1] = pack2bf(p0, p1);
            }

        __builtin_amdgcn_s_setprio(1);
#pragma unroll
        for (int nt = 0; nt < 2; nt++) {
            int rowb = (nt * 32 + l32) * 8;
#pragma unroll
            for (int ks = 0; ks < 4; ks++) {
                short8 vf = *(const short8*)(Vcur + (size_t)(rowb + ((ks * 2 + half) ^ sw)) * 8);
                acc[nt] = __builtin_amdgcn_mfma_f32_32x32x16_bf16(pa[ks].s8, vf, acc[nt], 0, 0, 0);
            }
        }
        __builtin_amdgcn_s_setprio(0);

        cur = (cur == 2) ? 0 : cur + 1;
    }

    float denom = lsum + __shfl_xor(lsum, 32);
    float inv_self = 1.0f / denom;

    int b_ = bh / 12, h = bh % 12;
#pragma unroll
    for (int nt = 0; nt < 2; nt++)
#pragma unroll
        for (int r = 0; r < 16; r++) {
            int qloc = (r & 3) + 8 * (r >> 2) + 4 * half;
            float invq = __shfl(inv_self, qloc);
            int q = qbase + qloc;
            int e = nt * 32 + l32;
            Ctx[((size_t)(b_ * 2048 + q)) * 768 + h * 64 + e] = f2bf(acc[nt][r] * invq);
        }
}

// ---------------- proj GEMM: out[8192,768] = Ctx @ W2^T + b, fp32 out ----------------
// r7 form: BK=32, tile 64x128, 768 blocks = exactly 3/CU, XCD remap.
__global__ __launch_bounds__(256) void gemm_out(
    const short* __restrict__ Ctx, const short* __restrict__ W,
    const float* __restrict__ bias, float* __restrict__ out)
{
    __shared__ short As[64 * 32];
    __shared__ short Bs[128 * 32];
    int tid = threadIdx.x;
    int w = tid >> 6, l = tid & 63;
    int lane16 = l & 15, quad = l >> 4;
    int wm = w & 1, wn = w >> 1;

    int fid = blockIdx.x + 6 * blockIdx.y;    // 0..767
    int c = fid & 7, s = fid >> 3;            // s in 0..95
    int my = c * 16 + s / 6;                  // 0..127
    int nx = s % 6;                           // 0..5
    int m0 = my * 64, n0 = nx * 128;

    floatx4 acc[2][4] = {};

    int srow = tid >> 2;        // 0..63
    int scol = (tid & 3) * 8;
    const short* Xg = Ctx + (size_t)(m0 + srow) * KDIM + scol;
    const short* Wg = W + (size_t)(n0 + srow) * KDIM + scol;
    short* AsW = As + (w * 16) * 32;
    short* BsW = Bs + (w * 16) * 32;

    for (int kb = 0; kb < KDIM; kb += 32) {
        __syncthreads();
        async16(Xg + kb,             AsW);
        async16(Wg + kb,             BsW);
        async16(Wg + kb + 64 * KDIM, BsW + 64 * 32);
        __syncthreads();
        short8 a[2], b[4];
#pragma unroll
        for (int mt = 0; mt < 2; mt++) a[mt] = *(const short8*)(As + (wm * 32 + mt * 16 + lane16) * 32 + quad * 8);
#pragma unroll
        for (int nt = 0; nt < 4; nt++) b[nt] = *(const short8*)(Bs + (wn * 64 + nt * 16 + lane16) * 32 + quad * 8);
#pragma unroll
        for (int mt = 0; mt < 2; mt++)
#pragma unroll
            for (int nt = 0; nt < 4; nt++)
                acc[mt][nt] = __builtin_amdgcn_mfma_f32_16x16x32_bf16(a[mt], b[nt], acc[mt][nt], 0, 0, 0);
    }

#pragma unroll
    for (int mt = 0; mt < 2; mt++) {
        int row = m0 + wm * 32 + mt * 16 + quad * 4;
#pragma unroll
        for (int nt = 0; nt < 4; nt++) {
            int col = n0 + wn * 64 + nt * 16 + lane16;
            float bv = bias[col];
#pragma unroll
            for (int r = 0; r < 4; r++)
                out[(size_t)(row + r) * 768 + col] = acc[mt][nt][r] + bv;
        }
    }
}

extern "C" void kernel_launch(void* const* d_in, const int* in_sizes, int n_in,
                              void* d_out, int out_size, void* d_ws, size_t ws_size,
                              hipStream_t stream) {
    const float* hs     = (const float*)d_in[0];
    const float* qkv_w  = (const float*)d_in[1];
    const float* qkv_b  = (const float*)d_in[2];
    const float* proj_w = (const float*)d_in[3];
    const float* proj_b = (const float*)d_in[4];
    float* out = (float*)d_out;

    short* Xb  = (short*)d_ws;                     // 8192*768 (dead after gemm_qkv; reused as Vt)
    short* W1b = Xb  + (size_t)8192 * 768;         // 2304*768
    short* W2b = W1b + (size_t)2304 * 768;         // 768*768
    short* Qb  = W2b + (size_t)768 * 768;          // 48*2048*64
    short* Kb  = Qb  + (size_t)8192 * 768;
    short* Vb  = Kb  + (size_t)8192 * 768;
    short* Ctx = Vb  + (size_t)8192 * 768;         // 8192*768
    short* Vt  = Xb;                               // [bh][64][2048] sigma-ordered, overlays dead Xb

    cvt_all<<<2048, 256, 0, stream>>>(hs, qkv_w, proj_w, Xb, W1b, W2b);

    gemm_qkv<<<dim3(18, 64), 256, 0, stream>>>(Xb, W1b, qkv_b, Qb, Kb, Vb);
    transpose_v<<<dim3(32, 48), 256, 0, stream>>>(Vb, Vt);
    attn<<<dim3(16, 48), 256, 0, stream>>>(Qb, Kb, Vt, Ctx);
    gemm_out<<<dim3(6, 128), 256, 0, stream>>>(Ctx, W2b, proj_b, out);
}